// Round 7
// baseline (316.185 us; speedup 1.0000x reference)
//
#include <hip/hip_runtime.h>
#include <hip/hip_bf16.h>
#include <cstddef>

#define B_ 32
#define T_ 2048
#define D_ 512
#define U_ 512

typedef __attribute__((ext_vector_type(8))) short bf16x8;   // 8 bf16 = 4 VGPRs
typedef __attribute__((ext_vector_type(4))) float f32x4;    // MFMA 16x16 accum

__device__ __forceinline__ unsigned short f2bf(float f) {
  union { float f; unsigned u; } x; x.f = f;
  unsigned r = x.u + 0x7fffu + ((x.u >> 16) & 1u);  // RNE
  return (unsigned short)(r >> 16);
}
__device__ __forceinline__ unsigned pack2bf(float a, float b) {
  return (unsigned)f2bf(a) | ((unsigned)f2bf(b) << 16);
}
__device__ __forceinline__ float tanh_fast(float x) {
  float e = __expf(2.0f * x);
  return 1.0f - 2.0f * __builtin_amdgcn_rcpf(e + 1.0f);
}

// ---------- kA: fused W2 pack (blocks 0..255) + q_proj/zero-init (blocks 256..319) ----------
// Pack: tile t = ut*16 + kg is 1KB: lane l holds 8 shorts =
// W2T[ut*16 + (l&15)][kg*32 + (l>>4)*8 + j]; k2's B-load is base + l*16B (coalesced).
__global__ void kA_prep(const float* __restrict__ W2, unsigned* __restrict__ W2P,
                        const float* __restrict__ query, const float* __restrict__ W1,
                        const float* __restrict__ W1b, const float* __restrict__ W2b,
                        float* __restrict__ qp, float* __restrict__ score,
                        float* __restrict__ ctx) {
  const int tid = threadIdx.x;              // 256
  if (blockIdx.x < 256) {
    #pragma unroll
    for (int ii = 0; ii < 2; ++ii) {
      int p = blockIdx.x * 512 + ii * 256 + tid;   // uint index 0..131071
      int j = (p & 3) * 2;
      int l = (p >> 2) & 63;
      int t = p >> 8;
      int u = (t >> 4) * 16 + (l & 15);
      int k = (t & 15) * 32 + ((l >> 4) << 3) + j;
      W2P[p] = pack2bf(W2[(size_t)k * U_ + u], W2[(size_t)(k + 1) * U_ + u]);
    }
  } else {
    __shared__ float qs[D_];
    const int blk = blockIdx.x - 256;       // 0..63
    const int b = blk >> 1, uhh = (blk & 1) * 256;
    qs[tid] = query[b * D_ + tid];
    qs[tid + 256] = query[b * D_ + tid + 256];
    __syncthreads();
    const int u = uhh + tid;
    float a0 = 0, a1 = 0, a2 = 0, a3 = 0, a4 = 0, a5 = 0, a6 = 0, a7 = 0;
    for (int d = 0; d < D_; d += 8) {
      a0 += qs[d + 0] * W1[(size_t)(d + 0) * U_ + u];
      a1 += qs[d + 1] * W1[(size_t)(d + 1) * U_ + u];
      a2 += qs[d + 2] * W1[(size_t)(d + 2) * U_ + u];
      a3 += qs[d + 3] * W1[(size_t)(d + 3) * U_ + u];
      a4 += qs[d + 4] * W1[(size_t)(d + 4) * U_ + u];
      a5 += qs[d + 5] * W1[(size_t)(d + 5) * U_ + u];
      a6 += qs[d + 6] * W1[(size_t)(d + 6) * U_ + u];
      a7 += qs[d + 7] * W1[(size_t)(d + 7) * U_ + u];
    }
    qp[b * U_ + u] = ((a0 + a1) + (a2 + a3)) + ((a4 + a5) + (a6 + a7)) + W1b[u] + W2b[u];
    const int gt = blk * 256 + tid;         // 0..16383
    ctx[gt] = 0.0f;
    #pragma unroll
    for (int i = 0; i < 4; ++i) score[i * 16384 + gt] = 0.0f;
  }
}

// ---------- kB: values fp32 -> VP bf16 packed in MFMA A-fragment order ----------
// Tile t = mt*16 + kg is 1KB: lane l holds A[mt*16+(l&15)][kg*32+(l>>4)*8+j].
// 2048 blocks x 32 rows; stage fp32 rows to LDS coalesced, emit packed coalesced.
__global__ void kB_pack(const float* __restrict__ values, unsigned* __restrict__ VP) {
  constexpr int LS = 260;                   // floats; 1040B stride (16B aligned)
  __shared__ float st[32 * LS];             // 33280 B
  const int mb = blockIdx.x;                // 32-row group = 2 m-tiles
  const int tid = threadIdx.x;
  #pragma unroll
  for (int half = 0; half < 2; ++half) {
    const float* vsrc = values + (size_t)mb * 32 * D_ + half * 256;
    #pragma unroll
    for (int it = 0; it < 8; ++it) {
      int i = tid + it * 256;               // 0..2047 float4
      int row = i >> 6, c4 = i & 63;
      float4 v = *(const float4*)(vsrc + (size_t)row * D_ + c4 * 4);
      *(float4*)&st[row * LS + c4 * 4] = v;
    }
    __syncthreads();
    #pragma unroll
    for (int n = 0; n < 16; ++n) {
      int q = tid + n * 256;                // 0..4095 uints this half
      int tm = q >> 11;                     // 0..1
      int kgl = (q >> 8) & 7;
      int lo = (q >> 2) & 63;
      int jp = q & 3;
      int mloc = tm * 16 + (lo & 15);
      int kloc = kgl * 32 + ((lo >> 4) << 3) + jp * 2;
      unsigned pk = pack2bf(st[mloc * LS + kloc], st[mloc * LS + kloc + 1]);
      VP[(size_t)((mb * 2 + tm) * 16 + half * 8 + kgl) * 256 + lo * 4 + jp] = pk;
    }
    __syncthreads();
  }
}

// ---------- k2_stream: barrier-free streaming MFMA GEMM from packed A (VP) + packed B (W2P) ----------
// Grid 2048: block = 64m x 256u-half; wave = 4m x 4u tiles. No LDS, no barriers.
// A triple-buffered (L3-latency), B double-buffered (L2-resident).
__global__ __launch_bounds__(256, 3) void k2_stream(
    const unsigned short* __restrict__ VP, const unsigned short* __restrict__ W2P,
    const float* __restrict__ qp, const float* __restrict__ Vw,
    float* __restrict__ score) {
  const int tid = threadIdx.x;
  const int bx = blockIdx.x;
  const int mbk = bx >> 1, uh = bx & 1;     // consecutive blocks share A (L2/L3 reuse)
  const int m0 = mbk * 64;
  const int b = m0 >> 11;
  const int l = tid & 63, w = tid >> 6;
  const int lr = l & 15, lq = l >> 4;

  f32x4 acc[4][4];                          // 64 AGPRs
  #pragma unroll
  for (int mi = 0; mi < 4; ++mi)
    #pragma unroll
    for (int ni = 0; ni < 4; ++ni) acc[mi][ni] = (f32x4){0.f, 0.f, 0.f, 0.f};

  const unsigned short* Ab = VP + (size_t)(mbk * 4) * 8192 + (size_t)l * 8;
  const unsigned short* Bb = W2P + (size_t)(uh * 16 + w * 4) * 8192 + (size_t)l * 8;

  bf16x8 Ar[3][4], Br[2][4];
  #pragma unroll
  for (int mi = 0; mi < 4; ++mi) Ar[0][mi] = *(const bf16x8*)(Ab + (size_t)mi * 8192);
  #pragma unroll
  for (int ni = 0; ni < 4; ++ni) Br[0][ni] = *(const bf16x8*)(Bb + (size_t)ni * 8192);
  #pragma unroll
  for (int mi = 0; mi < 4; ++mi) Ar[1][mi] = *(const bf16x8*)(Ab + (size_t)mi * 8192 + 512);

  #pragma unroll
  for (int kg = 0; kg < 16; ++kg) {         // K = 512 = 16 x 32
    const int ca = kg % 3, cb = kg & 1;
    if (kg < 14) {
      const int na = (kg + 2) % 3;
      #pragma unroll
      for (int mi = 0; mi < 4; ++mi)
        Ar[na][mi] = *(const bf16x8*)(Ab + (size_t)mi * 8192 + (size_t)(kg + 2) * 512);
    }
    if (kg < 15) {
      #pragma unroll
      for (int ni = 0; ni < 4; ++ni)
        Br[cb ^ 1][ni] = *(const bf16x8*)(Bb + (size_t)ni * 8192 + (size_t)(kg + 1) * 512);
    }
    #pragma unroll
    for (int ni = 0; ni < 4; ++ni)
      #pragma unroll
      for (int mi = 0; mi < 4; ++mi)
        acc[mi][ni] = __builtin_amdgcn_mfma_f32_16x16x32_bf16(Ar[ca][mi], Br[cb][ni], acc[mi][ni], 0, 0, 0);
  }

  // epilogue: tanh + weighted reduce over u (C/D: col=lane&15 -> u, row=lq*4+reg -> m)
  float sacc[4][4];
  #pragma unroll
  for (int mi = 0; mi < 4; ++mi)
    #pragma unroll
    for (int r = 0; r < 4; ++r) sacc[mi][r] = 0.0f;
  #pragma unroll
  for (int ni = 0; ni < 4; ++ni) {
    int u = uh * 256 + w * 64 + ni * 16 + lr;
    float qpv = qp[b * U_ + u], vv = Vw[u];
    #pragma unroll
    for (int mi = 0; mi < 4; ++mi)
      #pragma unroll
      for (int r = 0; r < 4; ++r)
        sacc[mi][r] += tanh_fast(acc[mi][ni][r] + qpv) * vv;
  }
  #pragma unroll
  for (int mi = 0; mi < 4; ++mi)
    #pragma unroll
    for (int r = 0; r < 4; ++r) {
      float v = sacc[mi][r];
      v += __shfl_xor(v, 1); v += __shfl_xor(v, 2);
      v += __shfl_xor(v, 4); v += __shfl_xor(v, 8);
      if (lr == 0) atomicAdd(&score[m0 + mi * 16 + lq * 4 + r], v);
    }
}

// ---------- k2_score_lds: fallback (R6 path) if workspace too small for VP ----------
__global__ __launch_bounds__(256, 3) void k2_score_lds(
    const float* __restrict__ values, const unsigned short* __restrict__ W2P,
    const float* __restrict__ qp, const float* __restrict__ Vw,
    float* __restrict__ score) {
  constexpr int LS = 264;
  __shared__ unsigned short av[64 * LS];
  __shared__ float qv[256];
  __shared__ float vwv[256];
  const int tid = threadIdx.x;
  const int bx = blockIdx.x;
  const int mt = bx >> 1, uh = bx & 1;
  const int m0 = mt * 64;
  const int b = m0 >> 11;
  const int ub = uh * 256;
  qv[tid] = qp[b * U_ + ub + tid];
  vwv[tid] = Vw[ub + tid];
  const int l = tid & 63, w = tid >> 6;
  const int lr = l & 15, lq = l >> 4;
  f32x4 acc[4][4];
  #pragma unroll
  for (int mi = 0; mi < 4; ++mi)
    #pragma unroll
    for (int ni = 0; ni < 4; ++ni) acc[mi][ni] = (f32x4){0.f, 0.f, 0.f, 0.f};
  const unsigned short* bw = W2P + (size_t)(uh * 16 + w * 4) * 8192 + (size_t)l * 8;
  const int abase = lr * LS + lq * 8;
  #pragma unroll
  for (int half = 0; half < 2; ++half) {
    const float4* vb = (const float4*)(values + (size_t)m0 * D_ + half * 256);
    #pragma unroll
    for (int it = 0; it < 16; ++it) {
      int i = tid + it * 256;
      int row = i >> 6, c4 = i & 63;
      float4 v = vb[(size_t)row * 128 + c4];
      uint2 p; p.x = pack2bf(v.x, v.y); p.y = pack2bf(v.z, v.w);
      *(uint2*)&av[row * LS + c4 * 4] = p;
    }
    __syncthreads();
    const int kg0 = half * 8;
    bf16x8 b0[4], b1[4];
    #pragma unroll
    for (int ni = 0; ni < 4; ++ni)
      b0[ni] = *(const bf16x8*)(bw + (size_t)ni * 8192 + (size_t)kg0 * 512);
    #pragma unroll
    for (int kk = 0; kk < 8; ++kk) {
      bf16x8* cur = (kk & 1) ? b1 : b0;
      bf16x8* nxt = (kk & 1) ? b0 : b1;
      if (kk < 7) {
        #pragma unroll
        for (int ni = 0; ni < 4; ++ni)
          nxt[ni] = *(const bf16x8*)(bw + (size_t)ni * 8192 + (size_t)(kg0 + kk + 1) * 512);
      }
      bf16x8 a[4];
      #pragma unroll
      for (int mi = 0; mi < 4; ++mi)
        a[mi] = *(const bf16x8*)&av[abase + mi * 16 * LS + kk * 32];
      #pragma unroll
      for (int ni = 0; ni < 4; ++ni)
        #pragma unroll
        for (int mi = 0; mi < 4; ++mi)
          acc[mi][ni] = __builtin_amdgcn_mfma_f32_16x16x32_bf16(a[mi], cur[ni], acc[mi][ni], 0, 0, 0);
    }
    __syncthreads();
  }
  float sacc[4][4];
  #pragma unroll
  for (int mi = 0; mi < 4; ++mi)
    #pragma unroll
    for (int r = 0; r < 4; ++r) sacc[mi][r] = 0.0f;
  #pragma unroll
  for (int ni = 0; ni < 4; ++ni) {
    int ul = w * 64 + ni * 16 + lr;
    float qpv = qv[ul], vv = vwv[ul];
    #pragma unroll
    for (int mi = 0; mi < 4; ++mi)
      #pragma unroll
      for (int r = 0; r < 4; ++r)
        sacc[mi][r] += tanh_fast(acc[mi][ni][r] + qpv) * vv;
  }
  #pragma unroll
  for (int mi = 0; mi < 4; ++mi)
    #pragma unroll
    for (int r = 0; r < 4; ++r) {
      float v = sacc[mi][r];
      v += __shfl_xor(v, 1); v += __shfl_xor(v, 2);
      v += __shfl_xor(v, 4); v += __shfl_xor(v, 8);
      if (lr == 0) atomicAdd(&score[m0 + mi * 16 + lq * 4 + r], v);
    }
}

// ---------- k3: softmax over T per batch (in-place) ----------
__global__ void k3_softmax(const float* __restrict__ score, float* __restrict__ attn) {
  __shared__ float red[8];
  const int b = blockIdx.x, tid = threadIdx.x;
  const float* s = score + b * T_;
  float v[8];
  float mx = -1e30f;
  #pragma unroll
  for (int i = 0; i < 8; ++i) { v[i] = s[tid + i * 256]; mx = fmaxf(mx, v[i]); }
  #pragma unroll
  for (int off = 1; off < 64; off <<= 1) mx = fmaxf(mx, __shfl_xor(mx, off));
  if ((tid & 63) == 0) red[tid >> 6] = mx;
  __syncthreads();
  mx = fmaxf(fmaxf(red[0], red[1]), fmaxf(red[2], red[3]));
  float sum = 0.0f;
  #pragma unroll
  for (int i = 0; i < 8; ++i) { v[i] = __expf(v[i] - mx); sum += v[i]; }
  #pragma unroll
  for (int off = 1; off < 64; off <<= 1) sum += __shfl_xor(sum, off);
  if ((tid & 63) == 0) red[4 + (tid >> 6)] = sum;
  __syncthreads();
  sum = (red[4] + red[5]) + (red[6] + red[7]);
  float inv = 1.0f / sum;
  #pragma unroll
  for (int i = 0; i < 8; ++i) attn[b * T_ + tid + i * 256] = v[i] * inv;
}

// ---------- k4: context[b,:] = sum_t attn[b,t] * values[b,t,:] ----------
__global__ void k4_ctx(const float* __restrict__ values, const float* __restrict__ attn,
                       float* __restrict__ ctx) {
  __shared__ float at[64];
  __shared__ float ps[512];
  const int blk = blockIdx.x;               // 1024 = 32 b x 32 t-chunks of 64
  const int b = blk >> 5, tc = blk & 31;
  const int tid = threadIdx.x;
  if (tid < 64) at[tid] = attn[b * T_ + tc * 64 + tid];
  __syncthreads();
  const int q = tid & 127;
  const int r0 = tid >> 7;
  const float4* vb = (const float4*)(values + ((size_t)b * T_ + tc * 64) * D_);
  float ax = 0.f, ay = 0.f, az = 0.f, aw = 0.f;
  #pragma unroll 8
  for (int tt = 0; tt < 32; ++tt) {
    int row = tt * 2 + r0;
    float4 v = vb[(size_t)row * 128 + q];
    float a = at[row];
    ax += a * v.x; ay += a * v.y; az += a * v.z; aw += a * v.w;
  }
  if (r0 == 1) { ps[4 * q] = ax; ps[4 * q + 1] = ay; ps[4 * q + 2] = az; ps[4 * q + 3] = aw; }
  __syncthreads();
  if (r0 == 0) {
    atomicAdd(&ctx[b * D_ + 4 * q + 0], ax + ps[4 * q + 0]);
    atomicAdd(&ctx[b * D_ + 4 * q + 1], ay + ps[4 * q + 1]);
    atomicAdd(&ctx[b * D_ + 4 * q + 2], az + ps[4 * q + 2]);
    atomicAdd(&ctx[b * D_ + 4 * q + 3], aw + ps[4 * q + 3]);
  }
}

extern "C" void kernel_launch(void* const* d_in, const int* in_sizes, int n_in,
                              void* d_out, int out_size, void* d_ws, size_t ws_size,
                              hipStream_t stream) {
  const float* query = (const float*)d_in[0];
  const float* values = (const float*)d_in[1];
  const float* W1w = (const float*)d_in[2];
  const float* W1b = (const float*)d_in[3];
  const float* W2w = (const float*)d_in[4];
  const float* W2b = (const float*)d_in[5];
  const float* Vw  = (const float*)d_in[6];
  // V_b (d_in[7]) is a constant shift under softmax -> dropped.

  float* out = (float*)d_out;
  float* ctx  = out;                 // [B, D]    = 16384 floats
  float* attn = out + B_ * D_;       // [B, T, 1] = 65536 floats
  float* score = attn;               // raw scores in attn region; k3 softmaxes in place

  char* ws = (char*)d_ws;
  unsigned* W2P = (unsigned*)ws;                             // 512 KB packed B
  float* qp    = (float*)(ws + 512 * 1024);                  // 64 KB
  unsigned* VP  = (unsigned*)(ws + 576 * 1024);              // 64 MB packed bf16 A
  const size_t VP_BYTES = (size_t)B_ * T_ * D_ * 2;          // 67108864
  const bool big_ws = ws_size >= 576 * 1024 + VP_BYTES;

  kA_prep<<<320, 256, 0, stream>>>(W2w, W2P, query, W1w, W1b, W2b, qp, score, ctx);
  if (big_ws) {
    kB_pack<<<2048, 256, 0, stream>>>(values, VP);
    k2_stream<<<2048, 256, 0, stream>>>((const unsigned short*)VP, (const unsigned short*)W2P,
                                        qp, Vw, score);
  } else {
    k2_score_lds<<<2048, 256, 0, stream>>>(values, (const unsigned short*)W2P, qp, Vw, score);
  }
  k3_softmax<<<32, 256, 0, stream>>>(score, attn);
  k4_ctx<<<1024, 256, 0, stream>>>(values, attn, ctx);
}

// Round 8
// 287.054 us; speedup vs baseline: 1.1015x; 1.1015x over previous
//
#include <hip/hip_runtime.h>
#include <hip/hip_bf16.h>
#include <cstddef>
#include <cstdint>

#define B_ 32
#define T_ 2048
#define D_ 512
#define U_ 512

typedef __attribute__((ext_vector_type(8))) short bf16x8;   // 8 bf16 = 4 VGPRs
typedef __attribute__((ext_vector_type(4))) float f32x4;    // MFMA 16x16 accum

__device__ __forceinline__ unsigned short f2bf(float f) {
  union { float f; unsigned u; } x; x.f = f;
  unsigned r = x.u + 0x7fffu + ((x.u >> 16) & 1u);  // RNE (off critical path)
  return (unsigned short)(r >> 16);
}
__device__ __forceinline__ unsigned pack2bf(float a, float b) {
  return (unsigned)f2bf(a) | ((unsigned)f2bf(b) << 16);
}
// fast pack: round-half-up (add 0x8000) + v_perm -> 3 VALU per 2 floats
__device__ __forceinline__ unsigned pack2bf_fast(float a, float b) {
  union { float f; unsigned u; } xa, xb; xa.f = a; xb.f = b;
  return __builtin_amdgcn_perm(xb.u + 0x8000u, xa.u + 0x8000u, 0x07060302u);
}
__device__ __forceinline__ float tanh_fast(float x) {
  float e = __expf(2.0f * x);
  return 1.0f - 2.0f * __builtin_amdgcn_rcpf(e + 1.0f);
}

#define AS1C(p) ((const __attribute__((address_space(1))) unsigned*)(p))
#define AS3(p)  ((__attribute__((address_space(3))) unsigned*)(p))

// ---------- kA: fused W2 pack (blocks 0..255) + q_proj/zero-init (blocks 256..319) ----------
// Pack: tile t = ut*16 + kg is 1KB: lane l holds 8 shorts =
// W2T[ut*16 + (l&15)][kg*32 + (l>>4)*8 + j]; k2's B-load is base + l*16B (coalesced).
__global__ void kA_prep(const float* __restrict__ W2, unsigned* __restrict__ W2P,
                        const float* __restrict__ query, const float* __restrict__ W1,
                        const float* __restrict__ W1b, const float* __restrict__ W2b,
                        float* __restrict__ qp, float* __restrict__ score,
                        float* __restrict__ ctx) {
  const int tid = threadIdx.x;              // 256
  if (blockIdx.x < 256) {
    #pragma unroll
    for (int ii = 0; ii < 2; ++ii) {
      int p = blockIdx.x * 512 + ii * 256 + tid;   // uint index 0..131071
      int j = (p & 3) * 2;
      int l = (p >> 2) & 63;
      int t = p >> 8;
      int u = (t >> 4) * 16 + (l & 15);
      int k = (t & 15) * 32 + ((l >> 4) << 3) + j;
      W2P[p] = pack2bf(W2[(size_t)k * U_ + u], W2[(size_t)(k + 1) * U_ + u]);
    }
  } else {
    __shared__ float qs[D_];
    const int blk = blockIdx.x - 256;       // 0..63
    const int b = blk >> 1, uhh = (blk & 1) * 256;
    qs[tid] = query[b * D_ + tid];
    qs[tid + 256] = query[b * D_ + tid + 256];
    __syncthreads();
    const int u = uhh + tid;
    float a0 = 0, a1 = 0, a2 = 0, a3 = 0, a4 = 0, a5 = 0, a6 = 0, a7 = 0;
    for (int d = 0; d < D_; d += 8) {
      a0 += qs[d + 0] * W1[(size_t)(d + 0) * U_ + u];
      a1 += qs[d + 1] * W1[(size_t)(d + 1) * U_ + u];
      a2 += qs[d + 2] * W1[(size_t)(d + 2) * U_ + u];
      a3 += qs[d + 3] * W1[(size_t)(d + 3) * U_ + u];
      a4 += qs[d + 4] * W1[(size_t)(d + 4) * U_ + u];
      a5 += qs[d + 5] * W1[(size_t)(d + 5) * U_ + u];
      a6 += qs[d + 6] * W1[(size_t)(d + 6) * U_ + u];
      a7 += qs[d + 7] * W1[(size_t)(d + 7) * U_ + u];
    }
    qp[b * U_ + u] = ((a0 + a1) + (a2 + a3)) + ((a4 + a5) + (a6 + a7)) + W1b[u] + W2b[u];
    const int gt = blk * 256 + tid;         // 0..16383
    ctx[gt] = 0.0f;
    #pragma unroll
    for (int i = 0; i < 4; ++i) score[i * 16384 + gt] = 0.0f;
  }
}

// ---------- k2: score[m] += sum_u tanh(values@W2 + qp) * Vw  (bf16 MFMA) ----------
// 64m x 256u-half blocks (grid 2048). A staged fp32 by global_load_lds DMA in K-eighths
// (64 floats/row), double-buffered; fp32->bf16 pack at fragment read (3 VALU / 2 floats).
// LDS layout: group g = 4 rows, stride 1040 B (+16 pad -> uniform 8-lanes/bank on b128).
__global__ __launch_bounds__(256, 2) void k2_dma(
    const float* __restrict__ values, const unsigned short* __restrict__ W2P,
    const float* __restrict__ qp, const float* __restrict__ Vw,
    float* __restrict__ score) {
  constexpr int GS = 260;                   // floats per group (256 data + 4 pad)
  __shared__ float av[2][16 * GS];          // 2 x 16640 B = 33280 B
  const int tid = threadIdx.x;
  const int bx = blockIdx.x;
  const int mt = bx >> 1, uh = bx & 1;      // block = m-tile x u-half
  const int m0 = mt * 64;                   // 2048%64==0: never crosses batch
  const int b = m0 >> 11;
  const int l = tid & 63, w = tid >> 6;
  const int lr = l & 15, lq = l >> 4;

  // DMA lane geometry: wave op j stages group g=w*4+j (4 rows x 64 floats):
  // lane l -> row g*4 + (l>>4), float col (l&15)*4; LDS dest = base + l*16B (HW).
  const int drow = l >> 4;
  const int dcol = (l & 15) * 4;

  f32x4 acc[4][4];                          // 64 acc regs
  #pragma unroll
  for (int mi = 0; mi < 4; ++mi)
    #pragma unroll
    for (int ni = 0; ni < 4; ++ni) acc[mi][ni] = (f32x4){0.f, 0.f, 0.f, 0.f};

  // packed-B: u-tile = uh*16 + w*4 + ni; short offset = ut*8192 + kg*512 + l*8
  const unsigned short* Bb = W2P + (size_t)(uh * 16 + w * 4) * 8192 + (size_t)l * 8;

  // stage eighth e into buffer p
  auto stage = [&](int e, int p) {
    #pragma unroll
    for (int j = 0; j < 4; ++j) {
      int g = w * 4 + j;
      const float* gp = values + (size_t)(m0 + g * 4 + drow) * D_ + e * 64 + dcol;
      __builtin_amdgcn_global_load_lds(AS1C(gp), AS3(&av[p][g * GS]), 16, 0, 0);
    }
  };

  bf16x8 Bf[2][2][4];                       // [parity][kq][ni]
  stage(0, 0);
  #pragma unroll
  for (int kq = 0; kq < 2; ++kq)
    #pragma unroll
    for (int ni = 0; ni < 4; ++ni)
      Bf[0][kq][ni] = *(const bf16x8*)(Bb + (size_t)ni * 8192 + (size_t)kq * 512);

  // A-frag base: row r=mi*16+lr -> group mi*4+(lr>>2), sub-row lr&3
  const int afb = (lr >> 2) * GS + (lr & 3) * 64 + lq * 8;

  for (int e = 0; e < 8; ++e) {
    const int p = e & 1;
    __syncthreads();                        // drains DMA(e) (issued one eighth ago)
    if (e < 7) {
      stage(e + 1, p ^ 1);                  // overlaps compute(e)
      #pragma unroll
      for (int kq = 0; kq < 2; ++kq)
        #pragma unroll
        for (int ni = 0; ni < 4; ++ni)
          Bf[p ^ 1][kq][ni] = *(const bf16x8*)(Bb + (size_t)ni * 8192 + (size_t)(2 * e + 2 + kq) * 512);
    }
    #pragma unroll
    for (int kq = 0; kq < 2; ++kq) {
      bf16x8 a[4];
      #pragma unroll
      for (int mi = 0; mi < 4; ++mi) {
        const float* ap = &av[p][mi * 4 * GS + afb + kq * 32];
        f32x4 f0 = *(const f32x4*)ap;
        f32x4 f1 = *(const f32x4*)(ap + 4);
        unsigned u0 = pack2bf_fast(f0.x, f0.y);
        unsigned u1 = pack2bf_fast(f0.z, f0.w);
        unsigned u2 = pack2bf_fast(f1.x, f1.y);
        unsigned u3 = pack2bf_fast(f1.z, f1.w);
        unsigned au[4] = {u0, u1, u2, u3};
        a[mi] = *(const bf16x8*)au;
      }
      #pragma unroll
      for (int ni = 0; ni < 4; ++ni)
        #pragma unroll
        for (int mi = 0; mi < 4; ++mi)
          acc[mi][ni] = __builtin_amdgcn_mfma_f32_16x16x32_bf16(a[mi], Bf[p][kq][ni], acc[mi][ni], 0, 0, 0);
    }
  }

  // epilogue: tanh + weighted reduce over u (C/D: col=lane&15 -> u, row=lq*4+reg -> m)
  float sacc[4][4];
  #pragma unroll
  for (int mi = 0; mi < 4; ++mi)
    #pragma unroll
    for (int r = 0; r < 4; ++r) sacc[mi][r] = 0.0f;
  #pragma unroll
  for (int ni = 0; ni < 4; ++ni) {
    int u = uh * 256 + w * 64 + ni * 16 + lr;
    float qpv = qp[b * U_ + u], vv = Vw[u];
    #pragma unroll
    for (int mi = 0; mi < 4; ++mi)
      #pragma unroll
      for (int r = 0; r < 4; ++r)
        sacc[mi][r] += tanh_fast(acc[mi][ni][r] + qpv) * vv;
  }
  #pragma unroll
  for (int mi = 0; mi < 4; ++mi)
    #pragma unroll
    for (int r = 0; r < 4; ++r) {
      float v = sacc[mi][r];
      v += __shfl_xor(v, 1); v += __shfl_xor(v, 2);
      v += __shfl_xor(v, 4); v += __shfl_xor(v, 8);
      if (lr == 0) atomicAdd(&score[m0 + mi * 16 + lq * 4 + r], v);
    }
}

// ---------- k3: softmax over T per batch (in-place: score region == attn region) ----------
__global__ void k3_softmax(const float* __restrict__ score, float* __restrict__ attn) {
  __shared__ float red[8];
  const int b = blockIdx.x, tid = threadIdx.x;  // 32 blocks x 256
  const float* s = score + b * T_;
  float v[8];
  float mx = -1e30f;
  #pragma unroll
  for (int i = 0; i < 8; ++i) { v[i] = s[tid + i * 256]; mx = fmaxf(mx, v[i]); }
  #pragma unroll
  for (int off = 1; off < 64; off <<= 1) mx = fmaxf(mx, __shfl_xor(mx, off));
  if ((tid & 63) == 0) red[tid >> 6] = mx;
  __syncthreads();
  mx = fmaxf(fmaxf(red[0], red[1]), fmaxf(red[2], red[3]));
  float sum = 0.0f;
  #pragma unroll
  for (int i = 0; i < 8; ++i) { v[i] = __expf(v[i] - mx); sum += v[i]; }
  #pragma unroll
  for (int off = 1; off < 64; off <<= 1) sum += __shfl_xor(sum, off);
  if ((tid & 63) == 0) red[4 + (tid >> 6)] = sum;
  __syncthreads();
  sum = (red[4] + red[5]) + (red[6] + red[7]);
  float inv = 1.0f / sum;
  #pragma unroll
  for (int i = 0; i < 8; ++i) attn[b * T_ + tid + i * 256] = v[i] * inv;
}

// ---------- k4: context[b,:] = sum_t attn[b,t] * values[b,t,:] ----------
__global__ void k4_ctx(const float* __restrict__ values, const float* __restrict__ attn,
                       float* __restrict__ ctx) {
  __shared__ float at[64];
  __shared__ float ps[512];
  const int blk = blockIdx.x;               // 1024 = 32 b x 32 t-chunks of 64
  const int b = blk >> 5, tc = blk & 31;
  const int tid = threadIdx.x;              // 256
  if (tid < 64) at[tid] = attn[b * T_ + tc * 64 + tid];
  __syncthreads();
  const int q = tid & 127;
  const int r0 = tid >> 7;
  const float4* vb = (const float4*)(values + ((size_t)b * T_ + tc * 64) * D_);
  float ax = 0.f, ay = 0.f, az = 0.f, aw = 0.f;
  #pragma unroll 8
  for (int tt = 0; tt < 32; ++tt) {
    int row = tt * 2 + r0;
    float4 v = vb[(size_t)row * 128 + q];
    float a = at[row];
    ax += a * v.x; ay += a * v.y; az += a * v.z; aw += a * v.w;
  }
  if (r0 == 1) { ps[4 * q] = ax; ps[4 * q + 1] = ay; ps[4 * q + 2] = az; ps[4 * q + 3] = aw; }
  __syncthreads();
  if (r0 == 0) {
    atomicAdd(&ctx[b * D_ + 4 * q + 0], ax + ps[4 * q + 0]);
    atomicAdd(&ctx[b * D_ + 4 * q + 1], ay + ps[4 * q + 1]);
    atomicAdd(&ctx[b * D_ + 4 * q + 2], az + ps[4 * q + 2]);
    atomicAdd(&ctx[b * D_ + 4 * q + 3], aw + ps[4 * q + 3]);
  }
}

extern "C" void kernel_launch(void* const* d_in, const int* in_sizes, int n_in,
                              void* d_out, int out_size, void* d_ws, size_t ws_size,
                              hipStream_t stream) {
  const float* query = (const float*)d_in[0];
  const float* values = (const float*)d_in[1];
  const float* W1w = (const float*)d_in[2];
  const float* W1b = (const float*)d_in[3];
  const float* W2w = (const float*)d_in[4];
  const float* W2b = (const float*)d_in[5];
  const float* Vw  = (const float*)d_in[6];
  // V_b (d_in[7]) is a constant shift under softmax -> dropped.

  float* out = (float*)d_out;
  float* ctx  = out;                 // [B, D]    = 16384 floats
  float* attn = out + B_ * D_;       // [B, T, 1] = 65536 floats
  float* score = attn;               // raw scores in attn region; k3 softmaxes in place

  char* ws = (char*)d_ws;            // needs 576 KB
  unsigned* W2P = (unsigned*)ws;                             // 512 KB packed bf16 B
  float* qp    = (float*)(ws + 512 * 1024);                  // 64 KB

  kA_prep<<<320, 256, 0, stream>>>(W2w, W2P, query, W1w, W1b, W2b, qp, score, ctx);
  k2_dma<<<2048, 256, 0, stream>>>(values, (const unsigned short*)W2P, qp, Vw, score);
  k3_softmax<<<32, 256, 0, stream>>>(score, attn);
  k4_ctx<<<1024, 256, 0, stream>>>(values, attn, ctx);
}

// Round 9
// 277.854 us; speedup vs baseline: 1.1380x; 1.0331x over previous
//
#include <hip/hip_runtime.h>
#include <hip/hip_bf16.h>
#include <cstddef>
#include <cstdint>

#define B_ 32
#define T_ 2048
#define D_ 512
#define U_ 512

typedef __attribute__((ext_vector_type(8))) short bf16x8;   // 8 bf16 = 4 VGPRs
typedef __attribute__((ext_vector_type(4))) float f32x4;    // MFMA 16x16 accum

__device__ __forceinline__ unsigned short f2bf(float f) {
  union { float f; unsigned u; } x; x.f = f;
  unsigned r = x.u + 0x7fffu + ((x.u >> 16) & 1u);  // RNE (off critical path)
  return (unsigned short)(r >> 16);
}
__device__ __forceinline__ unsigned pack2bf(float a, float b) {
  return (unsigned)f2bf(a) | ((unsigned)f2bf(b) << 16);
}
// fast pack: round-half-up (add 0x8000) + v_perm -> 3 VALU per 2 floats (validated R8)
__device__ __forceinline__ unsigned pack2bf_fast(float a, float b) {
  union { float f; unsigned u; } xa, xb; xa.f = a; xb.f = b;
  return __builtin_amdgcn_perm(xb.u + 0x8000u, xa.u + 0x8000u, 0x07060302u);
}
__device__ __forceinline__ float tanh_fast(float x) {
  float e = __expf(2.0f * x);
  return 1.0f - 2.0f * __builtin_amdgcn_rcpf(e + 1.0f);
}

#define AS1C(p) ((const __attribute__((address_space(1))) unsigned*)(p))
#define AS3(p)  ((__attribute__((address_space(3))) unsigned*)(p))

// ---------- kA: fused W2 pack (blocks 0..255) + q_proj/zero-init (blocks 256..319) ----------
__global__ void kA_prep(const float* __restrict__ W2, unsigned* __restrict__ W2P,
                        const float* __restrict__ query, const float* __restrict__ W1,
                        const float* __restrict__ W1b, const float* __restrict__ W2b,
                        float* __restrict__ qp, float* __restrict__ score,
                        float* __restrict__ ctx) {
  const int tid = threadIdx.x;              // 256
  if (blockIdx.x < 256) {
    #pragma unroll
    for (int ii = 0; ii < 2; ++ii) {
      int p = blockIdx.x * 512 + ii * 256 + tid;   // uint index 0..131071
      int j = (p & 3) * 2;
      int l = (p >> 2) & 63;
      int t = p >> 8;
      int u = (t >> 4) * 16 + (l & 15);
      int k = (t & 15) * 32 + ((l >> 4) << 3) + j;
      W2P[p] = pack2bf(W2[(size_t)k * U_ + u], W2[(size_t)(k + 1) * U_ + u]);
    }
  } else {
    __shared__ float qs[D_];
    const int blk = blockIdx.x - 256;       // 0..63
    const int b = blk >> 1, uhh = (blk & 1) * 256;
    qs[tid] = query[b * D_ + tid];
    qs[tid + 256] = query[b * D_ + tid + 256];
    __syncthreads();
    const int u = uhh + tid;
    float a0 = 0, a1 = 0, a2 = 0, a3 = 0, a4 = 0, a5 = 0, a6 = 0, a7 = 0;
    for (int d = 0; d < D_; d += 8) {
      a0 += qs[d + 0] * W1[(size_t)(d + 0) * U_ + u];
      a1 += qs[d + 1] * W1[(size_t)(d + 1) * U_ + u];
      a2 += qs[d + 2] * W1[(size_t)(d + 2) * U_ + u];
      a3 += qs[d + 3] * W1[(size_t)(d + 3) * U_ + u];
      a4 += qs[d + 4] * W1[(size_t)(d + 4) * U_ + u];
      a5 += qs[d + 5] * W1[(size_t)(d + 5) * U_ + u];
      a6 += qs[d + 6] * W1[(size_t)(d + 6) * U_ + u];
      a7 += qs[d + 7] * W1[(size_t)(d + 7) * U_ + u];
    }
    qp[b * U_ + u] = ((a0 + a1) + (a2 + a3)) + ((a4 + a5) + (a6 + a7)) + W1b[u] + W2b[u];
    const int gt = blk * 256 + tid;         // 0..16383
    ctx[gt] = 0.0f;
    #pragma unroll
    for (int i = 0; i < 4; ++i) score[i * 16384 + gt] = 0.0f;
  }
}

// ---------- k2: score[m] += sum_u tanh(values@W2 + qp) * Vw  (bf16 MFMA) ----------
// 64m x 256u-half blocks (grid 2048). A staged fp32 via global_load_lds DMA in K-eighths
// (64 floats/row), double-buffered LDS (2x16KB). XOR-swizzled layout: data chunk q (16B)
// of row r stored at position q^(r&15) -> fragment reads are bank-uniform (2 lanes/bank,
// free per m136). DMA implements the swizzle by permuting per-lane GLOBAL source chunks
// (LDS dest stays wave-uniform base + lane*16). fp32->bf16 pack at fragment read.
__global__ __launch_bounds__(256, 3) void k2_dma(
    const float* __restrict__ values, const unsigned short* __restrict__ W2P,
    const float* __restrict__ qp, const float* __restrict__ Vw,
    float* __restrict__ score) {
  __shared__ float av[2][4096];             // 2 x 64 rows x 64 floats = 2 x 16 KB
  const int tid = threadIdx.x;
  const int bx = blockIdx.x;
  const int mt = bx >> 1, uh = bx & 1;      // block = m-tile x u-half
  const int m0 = mt * 64;                   // 2048%64==0: never crosses batch
  const int b = m0 >> 11;
  const int l = tid & 63, w = tid >> 6;
  const int lr = l & 15, lq = l >> 4;

  // DMA lane geometry: wave op j stages group g=w*4+j (4 rows x 64 floats, 1KB):
  // lane l -> row 4g+(l>>4); fetches swizzled data chunk q = (l&15) ^ (row&15);
  // lands at LDS position l within the group (HW: base + l*16B).
  const int drow = l >> 4;
  const int dchunk = l & 15;

  f32x4 acc[4][4];                          // 64 acc regs
  #pragma unroll
  for (int mi = 0; mi < 4; ++mi)
    #pragma unroll
    for (int ni = 0; ni < 4; ++ni) acc[mi][ni] = (f32x4){0.f, 0.f, 0.f, 0.f};

  // packed-B: u-tile = uh*16 + w*4 + ni; short offset = ut*8192 + kg*512 + l*8
  const unsigned short* Bb = W2P + (size_t)(uh * 16 + w * 4) * 8192 + (size_t)l * 8;

  auto stage = [&](int e, int p) {          // stage K-eighth e into buffer p
    #pragma unroll
    for (int j = 0; j < 4; ++j) {
      int g = w * 4 + j;
      int row = g * 4 + drow;               // 0..63 within m-tile
      int q = dchunk ^ (row & 15);          // swizzled source chunk
      const float* gp = values + (size_t)(m0 + row) * D_ + e * 64 + q * 4;
      __builtin_amdgcn_global_load_lds(AS1C(gp), AS3(&av[p][g * 256]), 16, 0, 0);
    }
  };

  bf16x8 Bc[4], Bn[4];
  stage(0, 0);
  #pragma unroll
  for (int ni = 0; ni < 4; ++ni) Bc[ni] = *(const bf16x8*)(Bb + (size_t)ni * 8192);

  for (int kg = 0; kg < 16; ++kg) {         // K = 512 = 16 x 32
    const int e = kg >> 1, p = e & 1;
    if ((kg & 1) == 0) {
      __syncthreads();                      // drains DMA(e) (a full eighth in flight)
      if (e < 7) stage(e + 1, p ^ 1);       // overlaps compute of kg, kg+1
    }
    if (kg < 15) {
      #pragma unroll
      for (int ni = 0; ni < 4; ++ni)
        Bn[ni] = *(const bf16x8*)(Bb + (size_t)ni * 8192 + (size_t)(kg + 1) * 512);
    }
    const int kq = kg & 1;
    bf16x8 a[4];
    #pragma unroll
    for (int mi = 0; mi < 4; ++mi) {
      const int row = mi * 16 + lr;
      const int p0 = (kq * 8 + lq * 2) ^ lr;          // swizzled position of chunk q0
      f32x4 flo = *(const f32x4*)&av[p][row * 64 + (p0 << 2)];
      f32x4 fhi = *(const f32x4*)&av[p][row * 64 + ((p0 ^ 1) << 2)];
      unsigned au[4] = { pack2bf_fast(flo.x, flo.y), pack2bf_fast(flo.z, flo.w),
                         pack2bf_fast(fhi.x, fhi.y), pack2bf_fast(fhi.z, fhi.w) };
      a[mi] = *(const bf16x8*)au;
    }
    #pragma unroll
    for (int ni = 0; ni < 4; ++ni)
      #pragma unroll
      for (int mi = 0; mi < 4; ++mi)
        acc[mi][ni] = __builtin_amdgcn_mfma_f32_16x16x32_bf16(a[mi], Bc[ni], acc[mi][ni], 0, 0, 0);
    #pragma unroll
    for (int ni = 0; ni < 4; ++ni) Bc[ni] = Bn[ni];
  }

  // epilogue: tanh + weighted reduce over u (C/D: col=lane&15 -> u, row=lq*4+reg -> m)
  float sacc[4][4];
  #pragma unroll
  for (int mi = 0; mi < 4; ++mi)
    #pragma unroll
    for (int r = 0; r < 4; ++r) sacc[mi][r] = 0.0f;
  #pragma unroll
  for (int ni = 0; ni < 4; ++ni) {
    int u = uh * 256 + w * 64 + ni * 16 + lr;
    float qpv = qp[b * U_ + u], vv = Vw[u];
    #pragma unroll
    for (int mi = 0; mi < 4; ++mi)
      #pragma unroll
      for (int r = 0; r < 4; ++r)
        sacc[mi][r] += tanh_fast(acc[mi][ni][r] + qpv) * vv;
  }
  #pragma unroll
  for (int mi = 0; mi < 4; ++mi)
    #pragma unroll
    for (int r = 0; r < 4; ++r) {
      float v = sacc[mi][r];
      v += __shfl_xor(v, 1); v += __shfl_xor(v, 2);
      v += __shfl_xor(v, 4); v += __shfl_xor(v, 8);
      if (lr == 0) atomicAdd(&score[m0 + mi * 16 + lq * 4 + r], v);
    }
}

// ---------- k3: softmax over T per batch (in-place: score region == attn region) ----------
__global__ void k3_softmax(const float* __restrict__ score, float* __restrict__ attn) {
  __shared__ float red[8];
  const int b = blockIdx.x, tid = threadIdx.x;  // 32 blocks x 256
  const float* s = score + b * T_;
  float v[8];
  float mx = -1e30f;
  #pragma unroll
  for (int i = 0; i < 8; ++i) { v[i] = s[tid + i * 256]; mx = fmaxf(mx, v[i]); }
  #pragma unroll
  for (int off = 1; off < 64; off <<= 1) mx = fmaxf(mx, __shfl_xor(mx, off));
  if ((tid & 63) == 0) red[tid >> 6] = mx;
  __syncthreads();
  mx = fmaxf(fmaxf(red[0], red[1]), fmaxf(red[2], red[3]));
  float sum = 0.0f;
  #pragma unroll
  for (int i = 0; i < 8; ++i) { v[i] = __expf(v[i] - mx); sum += v[i]; }
  #pragma unroll
  for (int off = 1; off < 64; off <<= 1) sum += __shfl_xor(sum, off);
  if ((tid & 63) == 0) red[4 + (tid >> 6)] = sum;
  __syncthreads();
  sum = (red[4] + red[5]) + (red[6] + red[7]);
  float inv = 1.0f / sum;
  #pragma unroll
  for (int i = 0; i < 8; ++i) attn[b * T_ + tid + i * 256] = v[i] * inv;
}

// ---------- k4: context[b,:] = sum_t attn[b,t] * values[b,t,:] ----------
__global__ void k4_ctx(const float* __restrict__ values, const float* __restrict__ attn,
                       float* __restrict__ ctx) {
  __shared__ float at[64];
  __shared__ float ps[512];
  const int blk = blockIdx.x;               // 1024 = 32 b x 32 t-chunks of 64
  const int b = blk >> 5, tc = blk & 31;
  const int tid = threadIdx.x;              // 256
  if (tid < 64) at[tid] = attn[b * T_ + tc * 64 + tid];
  __syncthreads();
  const int q = tid & 127;
  const int r0 = tid >> 7;
  const float4* vb = (const float4*)(values + ((size_t)b * T_ + tc * 64) * D_);
  float ax = 0.f, ay = 0.f, az = 0.f, aw = 0.f;
  #pragma unroll 8
  for (int tt = 0; tt < 32; ++tt) {
    int row = tt * 2 + r0;
    float4 v = vb[(size_t)row * 128 + q];
    float a = at[row];
    ax += a * v.x; ay += a * v.y; az += a * v.z; aw += a * v.w;
  }
  if (r0 == 1) { ps[4 * q] = ax; ps[4 * q + 1] = ay; ps[4 * q + 2] = az; ps[4 * q + 3] = aw; }
  __syncthreads();
  if (r0 == 0) {
    atomicAdd(&ctx[b * D_ + 4 * q + 0], ax + ps[4 * q + 0]);
    atomicAdd(&ctx[b * D_ + 4 * q + 1], ay + ps[4 * q + 1]);
    atomicAdd(&ctx[b * D_ + 4 * q + 2], az + ps[4 * q + 2]);
    atomicAdd(&ctx[b * D_ + 4 * q + 3], aw + ps[4 * q + 3]);
  }
}

extern "C" void kernel_launch(void* const* d_in, const int* in_sizes, int n_in,
                              void* d_out, int out_size, void* d_ws, size_t ws_size,
                              hipStream_t stream) {
  const float* query = (const float*)d_in[0];
  const float* values = (const float*)d_in[1];
  const float* W1w = (const float*)d_in[2];
  const float* W1b = (const float*)d_in[3];
  const float* W2w = (const float*)d_in[4];
  const float* W2b = (const float*)d_in[5];
  const float* Vw  = (const float*)d_in[6];
  // V_b (d_in[7]) is a constant shift under softmax -> dropped.

  float* out = (float*)d_out;
  float* ctx  = out;                 // [B, D]    = 16384 floats
  float* attn = out + B_ * D_;       // [B, T, 1] = 65536 floats
  float* score = attn;               // raw scores in attn region; k3 softmaxes in place

  char* ws = (char*)d_ws;            // needs 576 KB
  unsigned* W2P = (unsigned*)ws;                             // 512 KB packed bf16 B
  float* qp    = (float*)(ws + 512 * 1024);                  // 64 KB

  kA_prep<<<320, 256, 0, stream>>>(W2w, W2P, query, W1w, W1b, W2b, qp, score, ctx);
  k2_dma<<<2048, 256, 0, stream>>>(values, (const unsigned short*)W2P, qp, Vw, score);
  k3_softmax<<<32, 256, 0, stream>>>(score, attn);
  k4_ctx<<<1024, 256, 0, stream>>>(values, attn, ctx);
}

// Round 10
// 276.225 us; speedup vs baseline: 1.1447x; 1.0059x over previous
//
#include <hip/hip_runtime.h>
#include <hip/hip_bf16.h>
#include <cstddef>
#include <cstdint>

#define B_ 32
#define T_ 2048
#define D_ 512
#define U_ 512

typedef __attribute__((ext_vector_type(8))) short bf16x8;   // 8 bf16 = 4 VGPRs
typedef __attribute__((ext_vector_type(4))) float f32x4;    // MFMA 16x16 accum

__device__ __forceinline__ unsigned short f2bf(float f) {
  union { float f; unsigned u; } x; x.f = f;
  unsigned r = x.u + 0x7fffu + ((x.u >> 16) & 1u);  // RNE (off critical path)
  return (unsigned short)(r >> 16);
}
__device__ __forceinline__ unsigned pack2bf(float a, float b) {
  return (unsigned)f2bf(a) | ((unsigned)f2bf(b) << 16);
}
__device__ __forceinline__ float tanh_fast(float x) {
  float e = __expf(2.0f * x);
  return 1.0f - 2.0f * __builtin_amdgcn_rcpf(e + 1.0f);
}

#define AS1C(p) ((const __attribute__((address_space(1))) unsigned*)(p))
#define AS3(p)  ((__attribute__((address_space(3))) unsigned*)(p))

// ---------- kA: fused W2 pack (blocks 0..255) + q_proj/zero-init (blocks 256..319) ----------
__global__ void kA_prep(const float* __restrict__ W2, unsigned* __restrict__ W2P,
                        const float* __restrict__ query, const float* __restrict__ W1,
                        const float* __restrict__ W1b, const float* __restrict__ W2b,
                        float* __restrict__ qp, float* __restrict__ score,
                        float* __restrict__ ctx) {
  const int tid = threadIdx.x;              // 256
  if (blockIdx.x < 256) {
    #pragma unroll
    for (int ii = 0; ii < 2; ++ii) {
      int p = blockIdx.x * 512 + ii * 256 + tid;   // uint index 0..131071
      int j = (p & 3) * 2;
      int l = (p >> 2) & 63;
      int t = p >> 8;
      int u = (t >> 4) * 16 + (l & 15);
      int k = (t & 15) * 32 + ((l >> 4) << 3) + j;
      W2P[p] = pack2bf(W2[(size_t)k * U_ + u], W2[(size_t)(k + 1) * U_ + u]);
    }
  } else {
    __shared__ float qs[D_];
    const int blk = blockIdx.x - 256;       // 0..63
    const int b = blk >> 1, uhh = (blk & 1) * 256;
    qs[tid] = query[b * D_ + tid];
    qs[tid + 256] = query[b * D_ + tid + 256];
    __syncthreads();
    const int u = uhh + tid;
    float a0 = 0, a1 = 0, a2 = 0, a3 = 0, a4 = 0, a5 = 0, a6 = 0, a7 = 0;
    for (int d = 0; d < D_; d += 8) {
      a0 += qs[d + 0] * W1[(size_t)(d + 0) * U_ + u];
      a1 += qs[d + 1] * W1[(size_t)(d + 1) * U_ + u];
      a2 += qs[d + 2] * W1[(size_t)(d + 2) * U_ + u];
      a3 += qs[d + 3] * W1[(size_t)(d + 3) * U_ + u];
      a4 += qs[d + 4] * W1[(size_t)(d + 4) * U_ + u];
      a5 += qs[d + 5] * W1[(size_t)(d + 5) * U_ + u];
      a6 += qs[d + 6] * W1[(size_t)(d + 6) * U_ + u];
      a7 += qs[d + 7] * W1[(size_t)(d + 7) * U_ + u];
    }
    qp[b * U_ + u] = ((a0 + a1) + (a2 + a3)) + ((a4 + a5) + (a6 + a7)) + W1b[u] + W2b[u];
    const int gt = blk * 256 + tid;         // 0..16383
    ctx[gt] = 0.0f;
    #pragma unroll
    for (int i = 0; i < 4; ++i) score[i * 16384 + gt] = 0.0f;
  }
}

// ---------- k2: score[m] += sum_u tanh(values@W2 + qp) * Vw  (bf16 MFMA) ----------
// 64m x 256u-half blocks (grid 2048). A staged fp32 via global_load_lds DMA in K-eighths,
// double-buffered LDS (2x16KB), XOR-swizzled (bank-conflict-free, verified R9: 0 conflicts).
// fp32->bf16 at fragment read via v_cvt_pk_bf16_f32 (1 VALU / 2 floats; was 3 with
// add+perm — the in-loop pack was ~38 kcy/CU of VALU, the top removable stall term).
__global__ __launch_bounds__(256, 3) void k2_dma(
    const float* __restrict__ values, const unsigned short* __restrict__ W2P,
    const float* __restrict__ qp, const float* __restrict__ Vw,
    float* __restrict__ score) {
  __shared__ float av[2][4096];             // 2 x 64 rows x 64 floats = 2 x 16 KB
  const int tid = threadIdx.x;
  const int bx = blockIdx.x;
  const int mt = bx >> 1, uh = bx & 1;      // block = m-tile x u-half
  const int m0 = mt * 64;                   // 2048%64==0: never crosses batch
  const int b = m0 >> 11;
  const int l = tid & 63, w = tid >> 6;
  const int lr = l & 15, lq = l >> 4;

  const int drow = l >> 4;
  const int dchunk = l & 15;

  f32x4 acc[4][4];                          // 64 acc regs
  #pragma unroll
  for (int mi = 0; mi < 4; ++mi)
    #pragma unroll
    for (int ni = 0; ni < 4; ++ni) acc[mi][ni] = (f32x4){0.f, 0.f, 0.f, 0.f};

  // packed-B: u-tile = uh*16 + w*4 + ni; short offset = ut*8192 + kg*512 + l*8
  const unsigned short* Bb = W2P + (size_t)(uh * 16 + w * 4) * 8192 + (size_t)l * 8;

  auto stage = [&](int e, int p) {          // stage K-eighth e into buffer p
    #pragma unroll
    for (int j = 0; j < 4; ++j) {
      int g = w * 4 + j;
      int row = g * 4 + drow;               // 0..63 within m-tile
      int q = dchunk ^ (row & 15);          // swizzled source chunk
      const float* gp = values + (size_t)(m0 + row) * D_ + e * 64 + q * 4;
      __builtin_amdgcn_global_load_lds(AS1C(gp), AS3(&av[p][g * 256]), 16, 0, 0);
    }
  };

  bf16x8 Bc[4], Bn[4];
  stage(0, 0);
  #pragma unroll
  for (int ni = 0; ni < 4; ++ni) Bc[ni] = *(const bf16x8*)(Bb + (size_t)ni * 8192);

  for (int kg = 0; kg < 16; ++kg) {         // K = 512 = 16 x 32
    const int e = kg >> 1, p = e & 1;
    if ((kg & 1) == 0) {
      __syncthreads();                      // drains DMA(e) (a full eighth in flight)
      if (e < 7) stage(e + 1, p ^ 1);       // overlaps compute of kg, kg+1
    }
    if (kg < 15) {
      #pragma unroll
      for (int ni = 0; ni < 4; ++ni)
        Bn[ni] = *(const bf16x8*)(Bb + (size_t)ni * 8192 + (size_t)(kg + 1) * 512);
    }
    const int kq = kg & 1;
    bf16x8 a[4];
    #pragma unroll
    for (int mi = 0; mi < 4; ++mi) {
      const int row = mi * 16 + lr;
      const int p0 = (kq * 8 + lq * 2) ^ lr;          // swizzled position of chunk q0
      f32x4 flo = *(const f32x4*)&av[p][row * 64 + (p0 << 2)];
      f32x4 fhi = *(const f32x4*)&av[p][row * 64 + ((p0 ^ 1) << 2)];
      union { bf16x8 v; __hip_bfloat162 h[4]; } A;
      A.h[0] = __float22bfloat162_rn(make_float2(flo.x, flo.y));
      A.h[1] = __float22bfloat162_rn(make_float2(flo.z, flo.w));
      A.h[2] = __float22bfloat162_rn(make_float2(fhi.x, fhi.y));
      A.h[3] = __float22bfloat162_rn(make_float2(fhi.z, fhi.w));
      a[mi] = A.v;
    }
    #pragma unroll
    for (int ni = 0; ni < 4; ++ni)
      #pragma unroll
      for (int mi = 0; mi < 4; ++mi)
        acc[mi][ni] = __builtin_amdgcn_mfma_f32_16x16x32_bf16(a[mi], Bc[ni], acc[mi][ni], 0, 0, 0);
    #pragma unroll
    for (int ni = 0; ni < 4; ++ni) Bc[ni] = Bn[ni];
  }

  // epilogue: tanh + weighted reduce over u (C/D: col=lane&15 -> u, row=lq*4+reg -> m)
  float sacc[4][4];
  #pragma unroll
  for (int mi = 0; mi < 4; ++mi)
    #pragma unroll
    for (int r = 0; r < 4; ++r) sacc[mi][r] = 0.0f;
  #pragma unroll
  for (int ni = 0; ni < 4; ++ni) {
    int u = uh * 256 + w * 64 + ni * 16 + lr;
    float qpv = qp[b * U_ + u], vv = Vw[u];
    #pragma unroll
    for (int mi = 0; mi < 4; ++mi)
      #pragma unroll
      for (int r = 0; r < 4; ++r)
        sacc[mi][r] += tanh_fast(acc[mi][ni][r] + qpv) * vv;
  }
  #pragma unroll
  for (int mi = 0; mi < 4; ++mi)
    #pragma unroll
    for (int r = 0; r < 4; ++r) {
      float v = sacc[mi][r];
      v += __shfl_xor(v, 1); v += __shfl_xor(v, 2);
      v += __shfl_xor(v, 4); v += __shfl_xor(v, 8);
      if (lr == 0) atomicAdd(&score[m0 + mi * 16 + lq * 4 + r], v);
    }
}

// ---------- k3: softmax over T per batch (in-place: score region == attn region) ----------
__global__ void k3_softmax(const float* __restrict__ score, float* __restrict__ attn) {
  __shared__ float red[8];
  const int b = blockIdx.x, tid = threadIdx.x;  // 32 blocks x 256
  const float* s = score + b * T_;
  float v[8];
  float mx = -1e30f;
  #pragma unroll
  for (int i = 0; i < 8; ++i) { v[i] = s[tid + i * 256]; mx = fmaxf(mx, v[i]); }
  #pragma unroll
  for (int off = 1; off < 64; off <<= 1) mx = fmaxf(mx, __shfl_xor(mx, off));
  if ((tid & 63) == 0) red[tid >> 6] = mx;
  __syncthreads();
  mx = fmaxf(fmaxf(red[0], red[1]), fmaxf(red[2], red[3]));
  float sum = 0.0f;
  #pragma unroll
  for (int i = 0; i < 8; ++i) { v[i] = __expf(v[i] - mx); sum += v[i]; }
  #pragma unroll
  for (int off = 1; off < 64; off <<= 1) sum += __shfl_xor(sum, off);
  if ((tid & 63) == 0) red[4 + (tid >> 6)] = sum;
  __syncthreads();
  sum = (red[4] + red[5]) + (red[6] + red[7]);
  float inv = 1.0f / sum;
  #pragma unroll
  for (int i = 0; i < 8; ++i) attn[b * T_ + tid + i * 256] = v[i] * inv;
}

// ---------- k4: context[b,:] = sum_t attn[b,t] * values[b,t,:] ----------
__global__ void k4_ctx(const float* __restrict__ values, const float* __restrict__ attn,
                       float* __restrict__ ctx) {
  __shared__ float at[64];
  __shared__ float ps[512];
  const int blk = blockIdx.x;               // 1024 = 32 b x 32 t-chunks of 64
  const int b = blk >> 5, tc = blk & 31;
  const int tid = threadIdx.x;              // 256
  if (tid < 64) at[tid] = attn[b * T_ + tc * 64 + tid];
  __syncthreads();
  const int q = tid & 127;
  const int r0 = tid >> 7;
  const float4* vb = (const float4*)(values + ((size_t)b * T_ + tc * 64) * D_);
  float ax = 0.f, ay = 0.f, az = 0.f, aw = 0.f;
  #pragma unroll 8
  for (int tt = 0; tt < 32; ++tt) {
    int row = tt * 2 + r0;
    float4 v = vb[(size_t)row * 128 + q];
    float a = at[row];
    ax += a * v.x; ay += a * v.y; az += a * v.z; aw += a * v.w;
  }
  if (r0 == 1) { ps[4 * q] = ax; ps[4 * q + 1] = ay; ps[4 * q + 2] = az; ps[4 * q + 3] = aw; }
  __syncthreads();
  if (r0 == 0) {
    atomicAdd(&ctx[b * D_ + 4 * q + 0], ax + ps[4 * q + 0]);
    atomicAdd(&ctx[b * D_ + 4 * q + 1], ay + ps[4 * q + 1]);
    atomicAdd(&ctx[b * D_ + 4 * q + 2], az + ps[4 * q + 2]);
    atomicAdd(&ctx[b * D_ + 4 * q + 3], aw + ps[4 * q + 3]);
  }
}

extern "C" void kernel_launch(void* const* d_in, const int* in_sizes, int n_in,
                              void* d_out, int out_size, void* d_ws, size_t ws_size,
                              hipStream_t stream) {
  const float* query = (const float*)d_in[0];
  const float* values = (const float*)d_in[1];
  const float* W1w = (const float*)d_in[2];
  const float* W1b = (const float*)d_in[3];
  const float* W2w = (const float*)d_in[4];
  const float* W2b = (const float*)d_in[5];
  const float* Vw  = (const float*)d_in[6];
  // V_b (d_in[7]) is a constant shift under softmax -> dropped.

  float* out = (float*)d_out;
  float* ctx  = out;                 // [B, D]    = 16384 floats
  float* attn = out + B_ * D_;       // [B, T, 1] = 65536 floats
  float* score = attn;               // raw scores in attn region; k3 softmaxes in place

  char* ws = (char*)d_ws;            // needs 576 KB
  unsigned* W2P = (unsigned*)ws;                             // 512 KB packed bf16 B
  float* qp    = (float*)(ws + 512 * 1024);                  // 64 KB

  kA_prep<<<320, 256, 0, stream>>>(W2w, W2P, query, W1w, W1b, W2b, qp, score, ctx);
  k2_dma<<<2048, 256, 0, stream>>>(values, (const unsigned short*)W2P, qp, Vw, score);
  k3_softmax<<<32, 256, 0, stream>>>(score, attn);
  k4_ctx<<<1024, 256, 0, stream>>>(values, attn, ctx);
}